// Round 8
// baseline (107.788 us; speedup 1.0000x reference)
//
#include <hip/hip_runtime.h>

// Bicubic (Catmull-Rom) warped interpolation, LDS-tiled, occupancy-optimized.
// img/delta_x/delta_y: [B,C,H,W] fp32; out: fp32 clipped to [0,1]. H=W=1024.
// 32x32 output tile / 128-thread block (2 waves); 48x48 fp32 patch in LDS
// (stride 49 -> 9.4KB -> 16 blocks/CU, 32 waves = full occupancy; small
// blocks desync stage/compute phases across the CU so staging overlaps
// compute of neighboring blocks). Delta loads for all 8 row-iterations are
// issued BEFORE staging so their ~900cy HBM latency hides under the staging
// phase. Lane = column (stride-1 -> 2 lanes/bank base). Out-of-patch taps
// (|delta| > ~6) take a rare fp32 global fallback.

#define HD 1024
#define WD 1024
#define TILE 32
#define HALO 8
#define SROWS 48   // staged rows & cols of valid data
#define SSTR 49    // LDS row stride in floats

__device__ __forceinline__ float cubic_gather_global(
    const float* __restrict__ p, int x0, int y0,
    float wxm1, float wx0, float wx1, float wx2,
    float wym1, float wy0, float wy1, float wy2)
{
    int cx0 = min(max(x0 - 1, 0), WD - 1);
    int cx1 = min(max(x0,     0), WD - 1);
    int cx2 = min(max(x0 + 1, 0), WD - 1);
    int cx3 = min(max(x0 + 2, 0), WD - 1);
    int cy0 = min(max(y0 - 1, 0), HD - 1);
    int cy1 = min(max(y0,     0), HD - 1);
    int cy2 = min(max(y0 + 1, 0), HD - 1);
    int cy3 = min(max(y0 + 2, 0), HD - 1);
    const float* r0 = p + (size_t)cy0 * WD;
    const float* r1 = p + (size_t)cy1 * WD;
    const float* r2 = p + (size_t)cy2 * WD;
    const float* r3 = p + (size_t)cy3 * WD;
    float s0 = wxm1 * r0[cx0] + wx0 * r0[cx1] + wx1 * r0[cx2] + wx2 * r0[cx3];
    float s1 = wxm1 * r1[cx0] + wx0 * r1[cx1] + wx1 * r1[cx2] + wx2 * r1[cx3];
    float s2 = wxm1 * r2[cx0] + wx0 * r2[cx1] + wx1 * r2[cx2] + wx2 * r2[cx3];
    float s3 = wxm1 * r3[cx0] + wx0 * r3[cx1] + wx1 * r3[cx2] + wx2 * r3[cx3];
    return wym1 * s0 + wy0 * s1 + wy1 * s2 + wy2 * s3;
}

__global__ __launch_bounds__(128) void bicubic_tile_kernel(
    const float* __restrict__ img,
    const float* __restrict__ dxp,
    const float* __restrict__ dyp,
    float* __restrict__ out)
{
    __shared__ float sm[SROWS * SSTR];

    const int bx = blockIdx.x * TILE;
    const int by = blockIdx.y * TILE;
    const int plane = blockIdx.z;
    const float* __restrict__ p = img + (size_t)plane * (size_t)(HD * WD);

    const int gx0 = bx - HALO;
    const int gy0 = by - HALO;
    const int tid = threadIdx.x;

    // ---- issue ALL delta loads first: their HBM latency (~900cy) hides
    // under the staging phase below (syncthreads need not drain vmcnt for
    // loads destined to VGPRs).
    const int col = bx + (tid & 31);
    const int rbase = by + (tid >> 5);
    const int didx0 = (plane << 20) | (rbase << 10) | col;

    float vdx[8], vdy[8];
    #pragma unroll
    for (int it = 0; it < 8; ++it) {
        vdx[it] = dxp[didx0 + it * 4096];
        vdy[it] = dyp[didx0 + it * 4096];
    }

    // ---- stage 48x48 patch at (gy0, gx0) into LDS (edge-clamped) ----
    if (gx0 >= 0 && gx0 + SROWS <= WD) {
        for (int s = tid; s < SROWS * (SROWS / 4); s += 128) {
            int r = s / (SROWS / 4);
            int q = s - r * (SROWS / 4);
            int gy = min(max(gy0 + r, 0), HD - 1);
            float4 v = *reinterpret_cast<const float4*>(p + (size_t)gy * WD + gx0 + 4 * q);
            int b = r * SSTR + 4 * q;
            sm[b + 0] = v.x; sm[b + 1] = v.y; sm[b + 2] = v.z; sm[b + 3] = v.w;
        }
    } else {
        for (int s = tid; s < SROWS * SROWS; s += 128) {
            int r = s / SROWS;
            int c = s - r * SROWS;
            int gy = min(max(gy0 + r, 0), HD - 1);
            int gx = min(max(gx0 + c, 0), WD - 1);
            sm[r * SSTR + c] = p[(size_t)gy * WD + gx];
        }
    }
    __syncthreads();

    // x_map = ((x + dx - 512)/511 + 1)*511.5 == (x-512)*s + 511.5 + dx*s
    const float s = 511.5f / 511.0f;
    const float colA = ((float)col - 512.0f) * s + 511.5f;
    const float yA0 = ((float)rbase - 512.0f) * s + 511.5f;
    const float yStep = 4.0f * s;

    #pragma unroll
    for (int it = 0; it < 8; ++it) {
        const int didx = didx0 + it * 4096;
        const float ddx = vdx[it];
        const float ddy = vdy[it];

        float x_map = fmaf(ddx, s, colA);
        float y_map = fmaf(ddy, s, yA0 + (float)it * yStep);

        float x0f = floorf(x_map);
        float y0f = floorf(y_map);
        float tx = x_map - x0f;
        float ty = y_map - y0f;
        int x0 = (int)x0f;
        int y0 = (int)y0f;

        float tx2 = tx * tx, tx3 = tx2 * tx;
        float wxm1 = (-tx3 + 2.0f * tx2 - tx) * 0.5f;
        float wx0  = (3.0f * tx3 - 5.0f * tx2 + 2.0f) * 0.5f;
        float wx1  = (-3.0f * tx3 + 4.0f * tx2 + tx) * 0.5f;
        float wx2  = 1.0f - (wxm1 + wx0 + wx1);

        float ty2 = ty * ty, ty3 = ty2 * ty;
        float wym1 = (-ty3 + 2.0f * ty2 - ty) * 0.5f;
        float wy0  = (3.0f * ty3 - 5.0f * ty2 + 2.0f) * 0.5f;
        float wy1  = (-3.0f * ty3 + 4.0f * ty2 + ty) * 0.5f;
        float wy2  = 1.0f - (wym1 + wy0 + wy1);

        // raw tap window (LDS holds edge-clamped values; no per-tap clamps)
        const int lx = x0 - 1 - gx0;
        const int ly = y0 - 1 - gy0;
        const bool inb = (lx >= 0) & (lx <= SROWS - 4) & (ly >= 0) & (ly <= SROWS - 4);

        float acc;
        if (inb) {
            const float* b = &sm[ly * SSTR + lx];
            float s0 = wxm1 * b[0 * SSTR + 0] + wx0 * b[0 * SSTR + 1] + wx1 * b[0 * SSTR + 2] + wx2 * b[0 * SSTR + 3];
            float s1 = wxm1 * b[1 * SSTR + 0] + wx0 * b[1 * SSTR + 1] + wx1 * b[1 * SSTR + 2] + wx2 * b[1 * SSTR + 3];
            float s2 = wxm1 * b[2 * SSTR + 0] + wx0 * b[2 * SSTR + 1] + wx1 * b[2 * SSTR + 2] + wx2 * b[2 * SSTR + 3];
            float s3 = wxm1 * b[3 * SSTR + 0] + wx0 * b[3 * SSTR + 1] + wx1 * b[3 * SSTR + 2] + wx2 * b[3 * SSTR + 3];
            acc = wym1 * s0 + wy0 * s1 + wy1 * s2 + wy2 * s3;
        } else {
            acc = cubic_gather_global(p, x0, y0, wxm1, wx0, wx1, wx2,
                                      wym1, wy0, wy1, wy2);
        }
        out[didx] = fminf(fmaxf(acc, 0.0f), 1.0f);
    }
}

extern "C" void kernel_launch(void* const* d_in, const int* in_sizes, int n_in,
                              void* d_out, int out_size, void* d_ws, size_t ws_size,
                              hipStream_t stream) {
    const float* img = (const float*)d_in[0];
    const float* dxp = (const float*)d_in[1];
    const float* dyp = (const float*)d_in[2];
    float* out = (float*)d_out;

    const int planes = in_sizes[0] / (HD * WD);  // B*C = 24
    dim3 grid(WD / TILE, HD / TILE, planes);
    bicubic_tile_kernel<<<grid, 128, 0, stream>>>(img, dxp, dyp, out);
}

// Round 9
// 99.139 us; speedup vs baseline: 1.0872x; 1.0872x over previous
//
#include <hip/hip_runtime.h>

// Bicubic (Catmull-Rom) warped interpolation, LDS-tiled + software-pipelined.
// img/delta_x/delta_y: [B,C,H,W] fp32; out: fp32 clipped to [0,1]. H=W=1024.
// 64x64 output tile / 256-thread block; 80x80 fp32 patch in LDS (stride 83,
// 26.6KB -> 6 blocks/CU). Lane = column. Delta loads hoisted (R6 win).
// NEW: branchless tap path (clamped LDS addrs, rare fallback overwrites) +
// explicit 2-deep pipeline: iteration it+1's 16 ds_reads issue before
// iteration it's math, hiding ~120cy LDS latency under ~100cy of VALU.

#define HD 1024
#define WD 1024
#define TILE 64
#define HALO 8
#define SROWS 80   // staged rows & cols of valid data
#define SSTR 83    // LDS row stride in floats (83*4B; 80*83*4 = 26.56KB)

__device__ __forceinline__ float cubic_gather_global(
    const float* __restrict__ p, int x0, int y0,
    float wxm1, float wx0, float wx1, float wx2,
    float wym1, float wy0, float wy1, float wy2)
{
    int cx0 = min(max(x0 - 1, 0), WD - 1);
    int cx1 = min(max(x0,     0), WD - 1);
    int cx2 = min(max(x0 + 1, 0), WD - 1);
    int cx3 = min(max(x0 + 2, 0), WD - 1);
    int cy0 = min(max(y0 - 1, 0), HD - 1);
    int cy1 = min(max(y0,     0), HD - 1);
    int cy2 = min(max(y0 + 1, 0), HD - 1);
    int cy3 = min(max(y0 + 2, 0), HD - 1);
    const float* r0 = p + (size_t)cy0 * WD;
    const float* r1 = p + (size_t)cy1 * WD;
    const float* r2 = p + (size_t)cy2 * WD;
    const float* r3 = p + (size_t)cy3 * WD;
    float s0 = wxm1 * r0[cx0] + wx0 * r0[cx1] + wx1 * r0[cx2] + wx2 * r0[cx3];
    float s1 = wxm1 * r1[cx0] + wx0 * r1[cx1] + wx1 * r1[cx2] + wx2 * r1[cx3];
    float s2 = wxm1 * r2[cx0] + wx0 * r2[cx1] + wx1 * r2[cx2] + wx2 * r2[cx3];
    float s3 = wxm1 * r3[cx0] + wx0 * r3[cx1] + wx1 * r3[cx2] + wx2 * r3[cx3];
    return wym1 * s0 + wy0 * s1 + wy1 * s2 + wy2 * s3;
}

__global__ __launch_bounds__(256) void bicubic_tile_kernel(
    const float* __restrict__ img,
    const float* __restrict__ dxp,
    const float* __restrict__ dyp,
    float* __restrict__ out)
{
    __shared__ float sm[SROWS * SSTR];

    const int bx = blockIdx.x * TILE;
    const int by = blockIdx.y * TILE;
    const int plane = blockIdx.z;
    const float* __restrict__ p = img + (size_t)plane * (size_t)(HD * WD);

    const int gx0 = bx - HALO;
    const int gy0 = by - HALO;
    const int tid = threadIdx.x;

    // ---- stage 80x80 patch at (gy0, gx0) into LDS (edge-clamped) ----
    if (gx0 >= 0 && gx0 + SROWS <= WD) {
        for (int s = tid; s < SROWS * (SROWS / 4); s += 256) {
            int r = s / (SROWS / 4);
            int q = s - r * (SROWS / 4);
            int gy = min(max(gy0 + r, 0), HD - 1);
            float4 v = *reinterpret_cast<const float4*>(p + (size_t)gy * WD + gx0 + 4 * q);
            int b = r * SSTR + 4 * q;
            sm[b + 0] = v.x; sm[b + 1] = v.y; sm[b + 2] = v.z; sm[b + 3] = v.w;
        }
    } else {
        for (int s = tid; s < SROWS * SROWS; s += 256) {
            int r = s / SROWS;
            int c = s - r * SROWS;
            int gy = min(max(gy0 + r, 0), HD - 1);
            int gx = min(max(gx0 + c, 0), WD - 1);
            sm[r * SSTR + c] = p[(size_t)gy * WD + gx];
        }
    }
    __syncthreads();

    // ---- compute: lane = column (64 consecutive cols/wave), 16 rows/thread
    const int col = bx + (tid & 63);
    const int rbase = by + (tid >> 6);
    const int didx0 = (plane << 20) | (rbase << 10) | col;

    // hoisted delta loads (R6 win: HBM latency hides under compute)
    float vdx[16], vdy[16];
    #pragma unroll
    for (int it = 0; it < 16; ++it) {
        vdx[it] = dxp[didx0 + it * 4096];
        vdy[it] = dyp[didx0 + it * 4096];
    }

    // x_map = ((x + dx - 512)/511 + 1)*511.5 == (x-512)*sc + 511.5 + dx*sc
    const float sc = 511.5f / 511.0f;
    const float colA = ((float)col - 512.0f) * sc + 511.5f;
    const float yA0 = ((float)rbase - 512.0f) * sc + 511.5f;
    const float yStep = 4.0f * sc;

    // 2-deep pipeline state (all indices compile-time after full unroll)
    float tp[2][16];
    float tx_[2], ty_[2];
    int x0_[2], y0_[2], inb_[2];

    // STAGE A: address math + issue 16 LDS reads (clamped -> branchless)
    #define STAGE_A(s_, it_) do {                                             \
        float x_map = fmaf(vdx[it_], sc, colA);                               \
        float y_map = fmaf(vdy[it_], sc, yA0 + (float)(it_) * yStep);         \
        float x0f = floorf(x_map);                                            \
        float y0f = floorf(y_map);                                            \
        tx_[s_] = x_map - x0f;                                                \
        ty_[s_] = y_map - y0f;                                                \
        int x0 = (int)x0f, y0 = (int)y0f;                                     \
        x0_[s_] = x0; y0_[s_] = y0;                                           \
        int lx = x0 - 1 - gx0, ly = y0 - 1 - gy0;                             \
        inb_[s_] = (lx >= 0) & (lx <= SROWS - 4) & (ly >= 0) & (ly <= SROWS - 4); \
        int lxc = min(max(lx, 0), SROWS - 4);                                 \
        int lyc = min(max(ly, 0), SROWS - 4);                                 \
        const float* b = &sm[lyc * SSTR + lxc];                               \
        tp[s_][0]  = b[0 * SSTR + 0]; tp[s_][1]  = b[0 * SSTR + 1];           \
        tp[s_][2]  = b[0 * SSTR + 2]; tp[s_][3]  = b[0 * SSTR + 3];           \
        tp[s_][4]  = b[1 * SSTR + 0]; tp[s_][5]  = b[1 * SSTR + 1];           \
        tp[s_][6]  = b[1 * SSTR + 2]; tp[s_][7]  = b[1 * SSTR + 3];           \
        tp[s_][8]  = b[2 * SSTR + 0]; tp[s_][9]  = b[2 * SSTR + 1];           \
        tp[s_][10] = b[2 * SSTR + 2]; tp[s_][11] = b[2 * SSTR + 3];           \
        tp[s_][12] = b[3 * SSTR + 0]; tp[s_][13] = b[3 * SSTR + 1];           \
        tp[s_][14] = b[3 * SSTR + 2]; tp[s_][15] = b[3 * SSTR + 3];           \
    } while (0)

    // STAGE B: weights + interpolation + rare fallback + store
    #define STAGE_B(s_, it_) do {                                             \
        float tx = tx_[s_], ty = ty_[s_];                                     \
        float tx2 = tx * tx, tx3 = tx2 * tx;                                  \
        float wxm1 = (-tx3 + 2.0f * tx2 - tx) * 0.5f;                         \
        float wx0  = (3.0f * tx3 - 5.0f * tx2 + 2.0f) * 0.5f;                 \
        float wx1  = (-3.0f * tx3 + 4.0f * tx2 + tx) * 0.5f;                  \
        float wx2  = 1.0f - (wxm1 + wx0 + wx1);                               \
        float ty2 = ty * ty, ty3 = ty2 * ty;                                  \
        float wym1 = (-ty3 + 2.0f * ty2 - ty) * 0.5f;                         \
        float wy0  = (3.0f * ty3 - 5.0f * ty2 + 2.0f) * 0.5f;                 \
        float wy1  = (-3.0f * ty3 + 4.0f * ty2 + ty) * 0.5f;                  \
        float wy2  = 1.0f - (wym1 + wy0 + wy1);                               \
        float s0 = wxm1 * tp[s_][0]  + wx0 * tp[s_][1]  + wx1 * tp[s_][2]  + wx2 * tp[s_][3];  \
        float s1 = wxm1 * tp[s_][4]  + wx0 * tp[s_][5]  + wx1 * tp[s_][6]  + wx2 * tp[s_][7];  \
        float s2 = wxm1 * tp[s_][8]  + wx0 * tp[s_][9]  + wx1 * tp[s_][10] + wx2 * tp[s_][11]; \
        float s3 = wxm1 * tp[s_][12] + wx0 * tp[s_][13] + wx1 * tp[s_][14] + wx2 * tp[s_][15]; \
        float acc = wym1 * s0 + wy0 * s1 + wy1 * s2 + wy2 * s3;               \
        if (!inb_[s_])                                                        \
            acc = cubic_gather_global(p, x0_[s_], y0_[s_], wxm1, wx0, wx1, wx2, \
                                      wym1, wy0, wy1, wy2);                   \
        out[didx0 + (it_) * 4096] = fminf(fmaxf(acc, 0.0f), 1.0f);            \
    } while (0)

    STAGE_A(0, 0);
    #pragma unroll
    for (int it = 0; it < 16; ++it) {
        const int cur = it & 1;
        const int nxt = cur ^ 1;
        if (it < 15) {
            if (nxt == 0) STAGE_A(0, it + 1); else STAGE_A(1, it + 1);
        }
        if (cur == 0) STAGE_B(0, it); else STAGE_B(1, it);
    }
    #undef STAGE_A
    #undef STAGE_B
}

extern "C" void kernel_launch(void* const* d_in, const int* in_sizes, int n_in,
                              void* d_out, int out_size, void* d_ws, size_t ws_size,
                              hipStream_t stream) {
    const float* img = (const float*)d_in[0];
    const float* dxp = (const float*)d_in[1];
    const float* dyp = (const float*)d_in[2];
    float* out = (float*)d_out;

    const int planes = in_sizes[0] / (HD * WD);  // B*C = 24
    dim3 grid(WD / TILE, HD / TILE, planes);
    bicubic_tile_kernel<<<grid, 256, 0, stream>>>(img, dxp, dyp, out);
}